// Round 1
// baseline (12623.134 us; speedup 1.0000x reference)
//
#include <hip/hip_runtime.h>

#define NB    1024      // batch
#define SL    300       // enc seq len
#define NT    150       // decode steps
#define NH    256       // hidden
#define LA    320       // ENC_MAX_LEN
#define NV    81        // vocab

// workspace float offsets
#define OFF_WATTT   0u           // [512][320]
#define OFF_WCOMBT  163840u      // [512][256]
#define OFF_WCATT   294912u      // [512][1024]
#define OFF_WFCT    819200u      // [256][81]
#define OFF_P1      839936u      // [81][320]
#define OFF_P2      865856u      // [81][256]
#define OFF_PE      886592u      // [256]
#define OFF_H0      886848u      // [1024][256]
#define OFF_H1      1148992u
#define OFF_C       1411136u
#define OFF_X       1673280u
#define OFF_LOSS    1935424u     // [1024]
#define OFF_XD      1936448u     // [1024] int

static __device__ __forceinline__ float warp_max(float v) {
    #pragma unroll
    for (int o = 32; o > 0; o >>= 1) v = fmaxf(v, __shfl_xor(v, o));
    return v;
}
static __device__ __forceinline__ float warp_sum(float v) {
    #pragma unroll
    for (int o = 32; o > 0; o >>= 1) v += __shfl_xor(v, o);
    return v;
}
static __device__ __forceinline__ float sigmf(float v) {
    return 1.f / (1.f + expf(-v));
}

// ---------------- init: state + positional-encoding row ----------------
__global__ __launch_bounds__(256) void k_init(float* __restrict__ h0, float* __restrict__ c,
                                              int* __restrict__ xd, float* __restrict__ loss,
                                              float* __restrict__ pe) {
    const int idx = blockIdx.x * 256 + threadIdx.x;
    if (idx < NB * NH) { h0[idx] = 0.f; c[idx] = 0.f; }
    if (idx < NB)      { xd[idx] = 1; loss[idx] = 0.f; }
    if (idx < NH / 2) {
        // div = exp(2i * (-ln(10000)/256)) * 300  (reference quirk: single pe row)
        float arg  = (float)(2 * idx) * (-0.03597789207803196f);
        float divf = expf(arg) * 300.0f;
        pe[2 * idx]     = (float)sin((double)divf);
        pe[2 * idx + 1] = (float)cos((double)divf);
    }
}

// ---------------- weight transposes ----------------
__global__ __launch_bounds__(256) void k_tr_att(const float* __restrict__ W, float* __restrict__ WT) {
    const int i = blockIdx.x * 256 + threadIdx.x;
    if (i < 512 * LA) { const int k = i / LA, l = i - k * LA; WT[i] = W[l * 512 + k]; }
}
__global__ __launch_bounds__(256) void k_tr_comb(const float* __restrict__ W, float* __restrict__ WT) {
    const int i = blockIdx.x * 256 + threadIdx.x;
    if (i < 512 * NH) { const int k = i / NH, j = i - k * NH; WT[i] = W[j * 512 + k]; }
}
__global__ __launch_bounds__(256) void k_tr_cat(const float* __restrict__ Wih, const float* __restrict__ Whh,
                                                float* __restrict__ WT) {
    const int i = blockIdx.x * 256 + threadIdx.x;
    if (i < 512 * 1024) {
        const int k = i >> 10, j = i & 1023;
        WT[i] = (k < 256) ? Wih[j * 256 + k] : Whh[j * 256 + (k - 256)];
    }
}
__global__ __launch_bounds__(256) void k_tr_fc(const float* __restrict__ W, float* __restrict__ WT) {
    const int i = blockIdx.x * 256 + threadIdx.x;
    if (i < 256 * NV) { const int k = i / NV, j = i - k * NV; WT[i] = W[j * 256 + k]; }
}

// ---------------- P1[v][l] = emb[v,:] . W_att[l, 0:256] ----------------
__global__ __launch_bounds__(320) void k_p1(const float* __restrict__ emb, const float* __restrict__ WattT,
                                            float* __restrict__ P1) {
    __shared__ float e[NH];
    const int v = blockIdx.x, tid = threadIdx.x;
    if (tid < NH) e[tid] = emb[v * NH + tid];
    __syncthreads();
    float a0 = 0.f, a1 = 0.f;
    #pragma unroll 8
    for (int k = 0; k < NH; k += 2) {
        a0 += e[k]     * WattT[k * LA + tid];
        a1 += e[k + 1] * WattT[(k + 1) * LA + tid];
    }
    P1[v * LA + tid] = a0 + a1;
}
// ---------------- P2[v][j] = emb[v,:] . W_comb[j, 0:256] ----------------
__global__ __launch_bounds__(256) void k_p2(const float* __restrict__ emb, const float* __restrict__ WcombT,
                                            float* __restrict__ P2) {
    __shared__ float e[NH];
    const int v = blockIdx.x, tid = threadIdx.x;
    e[tid] = emb[v * NH + tid];
    __syncthreads();
    float a0 = 0.f, a1 = 0.f;
    #pragma unroll 8
    for (int k = 0; k < NH; k += 2) {
        a0 += e[k]     * WcombT[k * NH + tid];
        a1 += e[k + 1] * WcombT[(k + 1) * NH + tid];
    }
    P2[v * NH + tid] = a0 + a1;
}

// ---------------- step kernel 1: z -> softmax -> context -> comb -> x ----------------
__global__ __launch_bounds__(320) void k_step1(
    const int* __restrict__ enc, const float* __restrict__ emb,
    const float* __restrict__ b_att, const float* __restrict__ b_comb,
    const float* __restrict__ h_prev, const int* __restrict__ xd,
    const float* __restrict__ WattT, const float* __restrict__ WcombT,
    const float* __restrict__ P1, const float* __restrict__ P2,
    const float* __restrict__ pe, float* __restrict__ x_out)
{
    const int r = blockIdx.x, tid = threadIdx.x;
    __shared__ float h_s[NH];
    __shared__ float p_s[LA];
    __shared__ float a_s[NH];
    __shared__ float part[3 * NV];
    __shared__ float cw[NV];
    __shared__ int   enc_s[SL];
    __shared__ float red[16];
    __shared__ int   xds;

    if (tid < NH) h_s[tid] = h_prev[r * NH + tid];
    if (tid < SL) enc_s[tid] = enc[r * SL + tid];
    if (tid == 0) xds = xd[r];
    __syncthreads();
    const int xv = xds;

    // z[l], l = tid (blockDim.x == 320)
    float z = P1[xv * LA + tid] + b_att[tid];
    {
        float z0 = 0.f, z1 = 0.f;
        #pragma unroll 8
        for (int k = 0; k < NH; k += 2) {
            z0 += h_s[k]     * WattT[(256 + k) * LA + tid];
            z1 += h_s[k + 1] * WattT[(257 + k) * LA + tid];
        }
        z += z0 + z1;
    }
    // block max over 320
    const int wid = tid >> 6;
    float wm = warp_max(z);
    if ((tid & 63) == 0) red[wid] = wm;
    __syncthreads();
    if (tid == 0) {
        float m = red[0];
        #pragma unroll
        for (int i = 1; i < 5; ++i) m = fmaxf(m, red[i]);
        red[15] = m;
    }
    __syncthreads();
    const float M = red[15];
    const float p = expf(z - M);
    p_s[tid] = p;
    float s1 = warp_sum(p);
    float s2 = warp_sum(tid < SL ? p : 0.f);
    if ((tid & 63) == 0) { red[wid] = s1; red[5 + wid] = s2; }
    __syncthreads();
    if (tid == 0) {
        float sa = 0.f, s3 = 0.f;
        #pragma unroll
        for (int i = 0; i < 5; ++i) { sa += red[i]; s3 += red[5 + i]; }
        red[10] = sa; red[11] = s3;
    }
    __syncthreads();
    const float S_all = red[10], S300 = red[11];

    // deterministic vocab binning of exp-weights (3 chunks of 100 positions)
    if (tid < 3 * NV) {
        const int chunk = tid / NV, v = tid - chunk * NV;
        const int l0 = chunk * 100;
        float s = 0.f;
        for (int l = l0; l < l0 + 100; ++l)
            if (enc_s[l] == v) s += p_s[l];
        part[chunk * NV + v] = s;
    }
    __syncthreads();
    if (tid < NV) cw[tid] = part[tid] + part[NV + tid] + part[2 * NV + tid];
    __syncthreads();

    // context a[h] = (sum_v cw[v]*emb[v,h] + S300*pe[h]) / S_all
    if (tid < NH) {
        float acc = S300 * pe[tid];
        for (int v = 0; v < NV; ++v) acc += cw[v] * emb[v * NH + tid];
        a_s[tid] = acc / S_all;
    }
    __syncthreads();

    // comb: x[j] = relu(P2[xv,j] + b_comb[j] + a . W_comb[j,256:512])
    if (tid < NH) {
        float acc = P2[xv * NH + tid] + b_comb[tid];
        float a0 = 0.f, a1 = 0.f;
        #pragma unroll 8
        for (int k = 0; k < NH; k += 2) {
            a0 += a_s[k]     * WcombT[(256 + k) * NH + tid];
            a1 += a_s[k + 1] * WcombT[(257 + k) * NH + tid];
        }
        acc += a0 + a1;
        x_out[r * NH + tid] = fmaxf(acc, 0.f);
    }
}

// ---------------- step kernel 2: gates GEMM + LSTM pointwise ----------------
// grid (8 j-tiles, 32 b-tiles), 256 threads. Output view [b][j][gate], gate in {i,f,g,o}.
__global__ __launch_bounds__(256) void k_step2(
    const float* __restrict__ x, const float* __restrict__ h_prev,
    float* __restrict__ h_next, float* __restrict__ c,
    const float* __restrict__ WcatT,
    const float* __restrict__ b_ih, const float* __restrict__ b_hh)
{
    const int jb = blockIdx.x * 32;
    const int bb = blockIdx.y * 32;
    const int tid = threadIdx.x;
    __shared__ float At[32][34];    // [k][b], padded
    __shared__ float Bt[32][128];   // [k][gate*32 + j]
    float acc[2][2][4];
    #pragma unroll
    for (int a = 0; a < 2; ++a)
        #pragma unroll
        for (int b2 = 0; b2 < 2; ++b2)
            #pragma unroll
            for (int g = 0; g < 4; ++g) acc[a][b2][g] = 0.f;

    const int tb = tid >> 4, tj = tid & 15;
    const int ar = tid >> 3, ak = (tid & 7) << 2;

    for (int kb = 0; kb < 16; ++kb) {
        const float* asrc = (kb < 8) ? (x + (bb + ar) * NH + kb * 32 + ak)
                                     : (h_prev + (bb + ar) * NH + (kb - 8) * 32 + ak);
        const float4 av = *(const float4*)asrc;
        At[ak + 0][ar] = av.x; At[ak + 1][ar] = av.y;
        At[ak + 2][ar] = av.z; At[ak + 3][ar] = av.w;
        #pragma unroll
        for (int s = 0; s < 4; ++s) {
            const int q = tid + s * 256;
            const int k = q >> 5, rem = q & 31;
            const int seg = rem >> 3, f4 = (rem & 7) << 2;
            const float4 bv = *(const float4*)(WcatT + (size_t)(kb * 32 + k) * 1024 + seg * 256 + jb + f4);
            *(float4*)&Bt[k][seg * 32 + f4] = bv;
        }
        __syncthreads();
        #pragma unroll
        for (int kk = 0; kk < 32; ++kk) {
            const float2 aval = *(const float2*)&At[kk][tb * 2];
            #pragma unroll
            for (int g = 0; g < 4; ++g) {
                const float2 bval = *(const float2*)&Bt[kk][g * 32 + tj * 2];
                acc[0][0][g] += aval.x * bval.x;
                acc[0][1][g] += aval.x * bval.y;
                acc[1][0][g] += aval.y * bval.x;
                acc[1][1][g] += aval.y * bval.y;
            }
        }
        __syncthreads();
    }
    #pragma unroll
    for (int bi = 0; bi < 2; ++bi)
        #pragma unroll
        for (int ji = 0; ji < 2; ++ji) {
            const int b = bb + tb * 2 + bi, j = jb + tj * 2 + ji;
            const float ig = acc[bi][ji][0] + b_ih[j]       + b_hh[j];
            const float fg = acc[bi][ji][1] + b_ih[256 + j] + b_hh[256 + j];
            const float gg = acc[bi][ji][2] + b_ih[512 + j] + b_hh[512 + j];
            const float og = acc[bi][ji][3] + b_ih[768 + j] + b_hh[768 + j];
            const float co = c[b * NH + j];
            const float c2 = sigmf(fg) * co + sigmf(ig) * tanhf(gg);
            const float h2 = sigmf(og) * tanhf(c2);
            c[b * NH + j] = c2;
            h_next[b * NH + j] = h2;
        }
}

// ---------------- step kernel 3: fc + logits out + loss + greedy argmax ----------------
__global__ __launch_bounds__(256) void k_step3(
    const float* __restrict__ h2v, const float* __restrict__ WfcT,
    const float* __restrict__ b_fc, const int* __restrict__ tgt,
    float* __restrict__ out_logits, float* __restrict__ loss_acc,
    int* __restrict__ xd, const int t)
{
    const int r = blockIdx.x, tid = threadIdx.x;
    __shared__ float h_s[NH];
    __shared__ float lg[NV];
    h_s[tid] = h2v[r * NH + tid];
    __syncthreads();
    if (tid < NV) {
        float a0 = b_fc[tid], a1 = 0.f;
        #pragma unroll 8
        for (int k = 0; k < NH; k += 2) {
            a0 += h_s[k]     * WfcT[k * NV + tid];
            a1 += h_s[k + 1] * WfcT[(k + 1) * NV + tid];
        }
        const float v = a0 + a1;
        lg[tid] = v;
        out_logits[(size_t)t * (NB * NV) + r * NV + tid] = v;
    }
    __syncthreads();
    if (tid == 0) {
        float m = lg[0]; int am = 0;
        for (int i = 1; i < NV; ++i) if (lg[i] > m) { m = lg[i]; am = i; }  // first-max
        float S = 0.f;
        for (int i = 0; i < NV; ++i) S += expf(lg[i] - m);
        const int y = tgt[r * NT + t];
        loss_acc[r] += -(lg[y] - m - logf(S));
        xd[r] = am;
    }
}

// ---------------- final: mean loss ----------------
__global__ __launch_bounds__(256) void k_final(const float* __restrict__ loss, float* __restrict__ dst) {
    const int tid = threadIdx.x;
    float v = loss[tid] + loss[tid + 256] + loss[tid + 512] + loss[tid + 768];
    v = warp_sum(v);
    __shared__ float red[4];
    if ((tid & 63) == 0) red[tid >> 6] = v;
    __syncthreads();
    if (tid == 0) dst[0] = (red[0] + red[1] + red[2] + red[3]) / (float)(NB * NT);
}

extern "C" void kernel_launch(void* const* d_in, const int* in_sizes, int n_in,
                              void* d_out, int out_size, void* d_ws, size_t ws_size,
                              hipStream_t stream) {
    const int*   enc    = (const int*)d_in[0];
    const int*   tgt    = (const int*)d_in[1];
    // d_in[2] target_lens: unused by the reference
    const float* emb    = (const float*)d_in[3];
    const float* W_att  = (const float*)d_in[4];
    const float* b_att  = (const float*)d_in[5];
    const float* W_comb = (const float*)d_in[6];
    const float* b_comb = (const float*)d_in[7];
    const float* W_ih   = (const float*)d_in[8];
    const float* b_ih   = (const float*)d_in[9];
    const float* W_hh   = (const float*)d_in[10];
    const float* b_hh   = (const float*)d_in[11];
    const float* W_fc   = (const float*)d_in[12];
    const float* b_fc   = (const float*)d_in[13];

    float* ws  = (float*)d_ws;
    float* out = (float*)d_out;
    int*   xd  = (int*)(ws + OFF_XD);

    // setup
    hipLaunchKernelGGL(k_init, dim3(1024), dim3(256), 0, stream,
                       ws + OFF_H0, ws + OFF_C, xd, ws + OFF_LOSS, ws + OFF_PE);
    hipLaunchKernelGGL(k_tr_att,  dim3(640),  dim3(256), 0, stream, W_att,  ws + OFF_WATTT);
    hipLaunchKernelGGL(k_tr_comb, dim3(512),  dim3(256), 0, stream, W_comb, ws + OFF_WCOMBT);
    hipLaunchKernelGGL(k_tr_cat,  dim3(2048), dim3(256), 0, stream, W_ih, W_hh, ws + OFF_WCATT);
    hipLaunchKernelGGL(k_tr_fc,   dim3(81),   dim3(256), 0, stream, W_fc, ws + OFF_WFCT);
    hipLaunchKernelGGL(k_p1, dim3(81), dim3(320), 0, stream, emb, ws + OFF_WATTT,  ws + OFF_P1);
    hipLaunchKernelGGL(k_p2, dim3(81), dim3(256), 0, stream, emb, ws + OFF_WCOMBT, ws + OFF_P2);

    for (int t = 0; t < NT; ++t) {
        float* hp = ws + ((t & 1) ? OFF_H1 : OFF_H0);
        float* hn = ws + ((t & 1) ? OFF_H0 : OFF_H1);
        hipLaunchKernelGGL(k_step1, dim3(1024), dim3(320), 0, stream,
                           enc, emb, b_att, b_comb, hp, xd,
                           ws + OFF_WATTT, ws + OFF_WCOMBT, ws + OFF_P1, ws + OFF_P2,
                           ws + OFF_PE, ws + OFF_X);
        hipLaunchKernelGGL(k_step2, dim3(8, 32), dim3(256), 0, stream,
                           ws + OFF_X, hp, hn, ws + OFF_C, ws + OFF_WCATT, b_ih, b_hh);
        hipLaunchKernelGGL(k_step3, dim3(1024), dim3(256), 0, stream,
                           hn, ws + OFF_WFCT, b_fc, tgt, out, ws + OFF_LOSS, xd, t);
    }
    hipLaunchKernelGGL(k_final, dim3(1), dim3(256), 0, stream,
                       ws + OFF_LOSS, out + (out_size - 1));
}